// Round 12
// baseline (1370.388 us; speedup 1.0000x reference)
//
#include <hip/hip_runtime.h>

#define DH 128   // D_IN == D_H == 128
#define TR 32    // rows per tile (per block)

typedef __attribute__((ext_vector_type(8))) short bf16x8;
typedef __attribute__((ext_vector_type(8))) unsigned short u16x8;
typedef __attribute__((ext_vector_type(4))) float f32x4;
typedef __attribute__((ext_vector_type(4))) int   i32x4;

__device__ inline unsigned rnd_bf16(float f){
  unsigned u = __builtin_bit_cast(unsigned, f);
  u += 0x7fffu + ((u >> 16) & 1u);   // RNE
  return u;
}
__device__ inline int pk2(float a, float b){
  unsigned ua = rnd_bf16(a), ub = rnd_bf16(b);
  return (int)((ua >> 16) | (ub & 0xffff0000u));
}
__device__ inline float fsigmoid(float v){
  float e = __builtin_amdgcn_exp2f(v * -1.442695040888963f);
  return __builtin_amdgcn_rcpf(1.0f + e);
}
__device__ inline float ftanhf(float v){
  float e = __builtin_amdgcn_exp2f(v * 2.885390081777927f); // e^{2v}
  return 1.0f - 2.0f * __builtin_amdgcn_rcpf(1.0f + e);
}

// Wf[hs 4][g 4][t 2][ks 8][lane 64] 16B fragments: lane (l15,lg) holds
// ncol = g*128 + hs*32 + t*16 + l15, k = ks*32 + lg*8 .. +8 (k<128: W_x, else W_h).
__global__ void prep_weights(const float* __restrict__ Wxi, const float* __restrict__ Whi, const float* __restrict__ bi,
                             const float* __restrict__ Wxf, const float* __restrict__ Whf, const float* __restrict__ bf_,
                             const float* __restrict__ Wxc, const float* __restrict__ Whc, const float* __restrict__ bc,
                             const float* __restrict__ Wxo, const float* __restrict__ Who, const float* __restrict__ bo,
                             u16x8* __restrict__ Wf, float* __restrict__ bcat){
  int gid  = blockIdx.x * 256 + threadIdx.x;   // 0..16383
  int lane = gid & 63;
  int ks   = (gid >> 6) & 7;
  int t    = (gid >> 9) & 1;
  int g    = (gid >> 10) & 3;
  int hsv  = (gid >> 12) & 3;
  int l15 = lane & 15, lg = lane >> 4;
  int hcol = hsv * 32 + t * 16 + l15;
  int kb   = ks * 32 + lg * 8;
  const float* Wx = (g == 0) ? Wxi : (g == 1) ? Wxf : (g == 2) ? Wxc : Wxo;
  const float* Wh = (g == 0) ? Whi : (g == 1) ? Whf : (g == 2) ? Whc : Who;
  u16x8 o;
  #pragma unroll
  for (int j = 0; j < 8; ++j){
    int k = kb + j;
    float v = (k < 128) ? Wx[k * DH + hcol] : Wh[(k - 128) * DH + hcol];
    o[j] = (unsigned short)(rnd_bf16(v) >> 16);
  }
  Wf[gid] = o;
  if (gid < 512){
    int gg = gid >> 7, hc = gid & 127;
    const float* bp = (gg == 0) ? bi : (gg == 1) ? bf_ : (gg == 2) ? bc : bo;
    bcat[gid] = bp[hc];
  }
}

// One 32-row tile per block. 256 thr = 4 waves; wave w owns h-cols
// [w*32,+32) for all 4 gates (lane-local elementwise). NT loads/stores.
// Single 16 KB LDS buffer reused: stage -> k-loop -> h-transpose -> store ->
// c-transpose -> store. 16 KB + 64 VGPR => up to 8 blocks/CU (32 waves).
__global__ __launch_bounds__(256, 8)
void lstm_fused(const float* __restrict__ x, const float* __restrict__ hin,
                const float* __restrict__ cin, const bf16x8* __restrict__ Wf,
                const float* __restrict__ bcat, float* __restrict__ out, int Btot){
  __shared__ __attribute__((aligned(16))) unsigned char smem[16384];
  bf16x8* xh  = (bf16x8*)smem;    // staging tile, 32 rows x 32 slots
  float*  tls = (float*)smem;     // epilogue transpose buffer, 32 x 128 f32

  const int tid = threadIdx.x;
  const int l   = tid & 63;
  const int hs  = tid >> 6;        // wave id = col-slice 0..3
  const int l15 = l & 15;
  const int lg  = l >> 4;          // 0..3
  const size_t rowb = (size_t)blockIdx.x * TR;

  // ---- staging loads (nontemporal: read-once)
  const int srow = tid >> 3;       // 0..31
  const int scol = (tid & 7) * 16; // float col base
  const float* px = x   + (rowb + srow) * DH + scol;
  const float* ph = hin + (rowb + srow) * DH + scol;
  f32x4 x0 = __builtin_nontemporal_load((const f32x4*)(px));
  f32x4 x1 = __builtin_nontemporal_load((const f32x4*)(px + 4));
  f32x4 x2 = __builtin_nontemporal_load((const f32x4*)(px + 8));
  f32x4 x3 = __builtin_nontemporal_load((const f32x4*)(px + 12));
  f32x4 h0 = __builtin_nontemporal_load((const f32x4*)(ph));
  f32x4 h1 = __builtin_nontemporal_load((const f32x4*)(ph + 4));
  f32x4 h2 = __builtin_nontemporal_load((const f32x4*)(ph + 8));
  f32x4 h3 = __builtin_nontemporal_load((const f32x4*)(ph + 12));

  // ---- c prefetch (nontemporal)
  float cr[2][2][4];
  #pragma unroll
  for (int m = 0; m < 2; ++m)
    #pragma unroll
    for (int t = 0; t < 2; ++t)
      #pragma unroll
      for (int r = 0; r < 4; ++r)
        cr[m][t][r] = __builtin_nontemporal_load(
            cin + (rowb + m * 16 + lg * 4 + r) * DH + hs * 32 + t * 16 + l15);

  // ---- pack + LDS write (slot swizzle s^(row&7); 2-way max = free)
  {
    const int sw = srow & 7;
    const int s0 = (tid & 7) * 2;        // x-half slots
    i32x4 p;
    p[0] = pk2(x0[0], x0[1]); p[1] = pk2(x0[2], x0[3]);
    p[2] = pk2(x1[0], x1[1]); p[3] = pk2(x1[2], x1[3]);
    xh[srow * 32 + ( s0          ^ sw)] = __builtin_bit_cast(bf16x8, p);
    p[0] = pk2(x2[0], x2[1]); p[1] = pk2(x2[2], x2[3]);
    p[2] = pk2(x3[0], x3[1]); p[3] = pk2(x3[2], x3[3]);
    xh[srow * 32 + ((s0 + 1)     ^ sw)] = __builtin_bit_cast(bf16x8, p);
    p[0] = pk2(h0[0], h0[1]); p[1] = pk2(h0[2], h0[3]);
    p[2] = pk2(h1[0], h1[1]); p[3] = pk2(h1[2], h1[3]);
    xh[srow * 32 + ((16 + s0)    ^ sw)] = __builtin_bit_cast(bf16x8, p);
    p[0] = pk2(h2[0], h2[1]); p[1] = pk2(h2[2], h2[3]);
    p[2] = pk2(h3[0], h3[1]); p[3] = pk2(h3[2], h3[3]);
    xh[srow * 32 + ((16 + s0 + 1)^ sw)] = __builtin_bit_cast(bf16x8, p);
  }
  __syncthreads();

  float bb[4][2];
  #pragma unroll
  for (int g = 0; g < 4; ++g)
    #pragma unroll
    for (int t = 0; t < 2; ++t)
      bb[g][t] = bcat[g * 128 + hs * 32 + t * 16 + l15];

  const bf16x8* wv = Wf + (size_t)hs * 4096 + l;  // [(g*2+t)*8+ks] stride 64

  f32x4 acc[2][4][2];
  #pragma unroll
  for (int m = 0; m < 2; ++m)
    #pragma unroll
    for (int g = 0; g < 4; ++g)
      #pragma unroll
      for (int t = 0; t < 2; ++t)
        acc[m][g][t] = (f32x4){0.f, 0.f, 0.f, 0.f};

  #pragma unroll
  for (int ks = 0; ks < 8; ++ks){
    bf16x8 a[2];
    #pragma unroll
    for (int m = 0; m < 2; ++m){
      const int row = m * 16 + l15;
      a[m] = xh[row * 32 + ((ks * 4 + lg) ^ (row & 7))];
    }
    #pragma unroll
    for (int g = 0; g < 4; ++g){
      #pragma unroll
      for (int t = 0; t < 2; ++t){
        bf16x8 bw = wv[(((g * 2 + t) * 8) + ks) * 64];
        acc[0][g][t] = __builtin_amdgcn_mfma_f32_16x16x32_bf16(a[0], bw, acc[0][g][t], 0, 0, 0);
        acc[1][g][t] = __builtin_amdgcn_mfma_f32_16x16x32_bf16(a[1], bw, acc[1][g][t], 0, 0, 0);
      }
    }
  }
  __syncthreads();   // k-loop LDS reads done everywhere; safe to reuse smem

  // ---- gate math; h -> LDS transpose (swizzle col^((row&7)<<2)); c -> cr
  #pragma unroll
  for (int m = 0; m < 2; ++m){
    #pragma unroll
    for (int r = 0; r < 4; ++r){
      const int rl = m * 16 + lg * 4 + r;       // local row 0..31
      const int swp = (rl & 7) << 2;
      #pragma unroll
      for (int t = 0; t < 2; ++t){
        const int c = hs * 32 + t * 16 + l15;   // col 0..127
        float gi = acc[m][0][t][r] + bb[0][t];
        float gf = acc[m][1][t][r] + bb[1][t];
        float gc = acc[m][2][t][r] + bb[2][t];
        float go = acc[m][3][t][r] + bb[3][t];
        float i_t = fsigmoid(gi);
        float f_t = fsigmoid(gf);
        float g_t = ftanhf(gc);
        float o_t = fsigmoid(go);
        float cn = f_t * cr[m][t][r] + i_t * g_t;
        float hn = o_t * ftanhf(cn);
        tls[rl * DH + (c ^ swp)] = hn;
        cr[m][t][r] = cn;                        // stash c_new
      }
    }
  }
  __syncthreads();

  // ---- h stores: wave hs owns rows [hs*8,+8); lane l -> row j*2+(l>>5),
  // colf (l&31)*4 => each instruction = 1KiB contiguous NT burst.
  const size_t o1 = (size_t)Btot * DH;
  const int wcol = (l & 31) * 4;
  #pragma unroll
  for (int j = 0; j < 4; ++j){
    const int row = hs * 8 + j * 2 + (l >> 5);
    const int sw2 = (row & 7) << 2;
    f32x4 vh = *(const f32x4*)&tls[row * DH + (wcol ^ sw2)];
    float* po = out + (rowb + row) * DH + wcol;
    __builtin_nontemporal_store(vh, (f32x4*)(po));
    __builtin_nontemporal_store(vh, (f32x4*)(po + o1));
  }
  __syncthreads();   // h reads done; reuse LDS for c

  #pragma unroll
  for (int m = 0; m < 2; ++m){
    #pragma unroll
    for (int r = 0; r < 4; ++r){
      const int rl = m * 16 + lg * 4 + r;
      const int swp = (rl & 7) << 2;
      #pragma unroll
      for (int t = 0; t < 2; ++t){
        const int c = hs * 32 + t * 16 + l15;
        tls[rl * DH + (c ^ swp)] = cr[m][t][r];
      }
    }
  }
  __syncthreads();

  #pragma unroll
  for (int j = 0; j < 4; ++j){
    const int row = hs * 8 + j * 2 + (l >> 5);
    const int sw2 = (row & 7) << 2;
    f32x4 vc = *(const f32x4*)&tls[row * DH + (wcol ^ sw2)];
    __builtin_nontemporal_store(vc, (f32x4*)(out + 2 * o1 + (rowb + row) * DH + wcol));
  }
}

extern "C" void kernel_launch(void* const* d_in, const int* in_sizes, int n_in,
                              void* d_out, int out_size, void* d_ws, size_t ws_size,
                              hipStream_t stream){
  const float* x  = (const float*)d_in[0];
  const float* ht = (const float*)d_in[1];
  const float* ct = (const float*)d_in[2];
  u16x8* Wf   = (u16x8*)d_ws;                        // 16384 * 16B = 256KB
  float* bcat = (float*)((char*)d_ws + 16384 * 16);  // +2KB
  const int Btot = in_sizes[0] / DH;

  prep_weights<<<64, 256, 0, stream>>>(
      (const float*)d_in[3],  (const float*)d_in[4],  (const float*)d_in[5],
      (const float*)d_in[6],  (const float*)d_in[7],  (const float*)d_in[8],
      (const float*)d_in[9],  (const float*)d_in[10], (const float*)d_in[11],
      (const float*)d_in[12], (const float*)d_in[13], (const float*)d_in[14],
      Wf, bcat);

  lstm_fused<<<Btot / TR, 256, 0, stream>>>(x, ht, ct, (const bf16x8*)Wf, bcat,
                                            (float*)d_out, Btot);
}

// Round 13
// 435.338 us; speedup vs baseline: 3.1479x; 3.1479x over previous
//
#include <hip/hip_runtime.h>

#define DH 128   // D_IN == D_H == 128
#define TR 32    // rows per sub-tile; block does 2 sub-tiles

typedef __attribute__((ext_vector_type(8))) short bf16x8;
typedef __attribute__((ext_vector_type(8))) unsigned short u16x8;
typedef __attribute__((ext_vector_type(4))) float f32x4;
typedef __attribute__((ext_vector_type(4))) int   i32x4;

__device__ inline unsigned rnd_bf16(float f){
  unsigned u = __builtin_bit_cast(unsigned, f);
  u += 0x7fffu + ((u >> 16) & 1u);   // RNE
  return u;
}
__device__ inline int pk2(float a, float b){
  unsigned ua = rnd_bf16(a), ub = rnd_bf16(b);
  return (int)((ua >> 16) | (ub & 0xffff0000u));
}
__device__ inline float fsigmoid(float v){
  float e = __builtin_amdgcn_exp2f(v * -1.442695040888963f);
  return __builtin_amdgcn_rcpf(1.0f + e);
}
__device__ inline float ftanhf(float v){
  float e = __builtin_amdgcn_exp2f(v * 2.885390081777927f); // e^{2v}
  return 1.0f - 2.0f * __builtin_amdgcn_rcpf(1.0f + e);
}

// Wf[hs 4][g 4][t 2][ks 8][lane 64] 16B fragments: lane (l15,lg) holds
// ncol = g*128 + hs*32 + t*16 + l15, k = ks*32 + lg*8 .. +8 (k<128: W_x, else W_h).
__global__ void prep_weights(const float* __restrict__ Wxi, const float* __restrict__ Whi, const float* __restrict__ bi,
                             const float* __restrict__ Wxf, const float* __restrict__ Whf, const float* __restrict__ bf_,
                             const float* __restrict__ Wxc, const float* __restrict__ Whc, const float* __restrict__ bc,
                             const float* __restrict__ Wxo, const float* __restrict__ Who, const float* __restrict__ bo,
                             u16x8* __restrict__ Wf, float* __restrict__ bcat){
  int gid  = blockIdx.x * 256 + threadIdx.x;   // 0..16383
  int lane = gid & 63;
  int ks   = (gid >> 6) & 7;
  int t    = (gid >> 9) & 1;
  int g    = (gid >> 10) & 3;
  int hsv  = (gid >> 12) & 3;
  int l15 = lane & 15, lg = lane >> 4;
  int hcol = hsv * 32 + t * 16 + l15;
  int kb   = ks * 32 + lg * 8;
  const float* Wx = (g == 0) ? Wxi : (g == 1) ? Wxf : (g == 2) ? Wxc : Wxo;
  const float* Wh = (g == 0) ? Whi : (g == 1) ? Whf : (g == 2) ? Whc : Who;
  u16x8 o;
  #pragma unroll
  for (int j = 0; j < 8; ++j){
    int k = kb + j;
    float v = (k < 128) ? Wx[k * DH + hcol] : Wh[(k - 128) * DH + hcol];
    o[j] = (unsigned short)(rnd_bf16(v) >> 16);
  }
  Wf[gid] = o;
  if (gid < 512){
    int gg = gid >> 7, hc = gid & 127;
    const float* bp = (gg == 0) ? bi : (gg == 1) ? bf_ : (gg == 2) ? bc : bo;
    bcat[gid] = bp[hc];
  }
}

// 2-tile pipelined block, register-audited. 256 thr = 4 waves; wave w owns
// h-cols [w*32,+32) for all 4 gates. Tile1 x/h loads issue inside tile0's
// k-loop (latency hidden under MFMA+weight loads); cr1 issues under epi0.
// NT loads/stores; epilogue 1KiB-contiguous store bursts; LDS 2x16KB.
__global__ __launch_bounds__(256, 4)
void lstm_fused(const float* __restrict__ x, const float* __restrict__ hin,
                const float* __restrict__ cin, const bf16x8* __restrict__ Wf,
                const float* __restrict__ bcat, float* __restrict__ out, int Btot){
  __shared__ __attribute__((aligned(16))) bf16x8 buf0[TR * 32];  // 16 KB
  __shared__ __attribute__((aligned(16))) bf16x8 buf1[TR * 32];  // 16 KB

  const int tid = threadIdx.x;
  const int l   = tid & 63;
  const int hs  = tid >> 6;        // wave id = col-slice 0..3
  const int l15 = l & 15;
  const int lg  = l >> 4;          // 0..3
  const size_t rowb0 = (size_t)blockIdx.x * (2 * TR);
  const size_t rowb1 = rowb0 + TR;

  const int srow = tid >> 3;       // 0..31
  const int scol = (tid & 7) * 16; // float col base
  const int swz  = srow & 7;
  const int s0   = (tid & 7) * 2;  // x-half slot base

  const bf16x8* wv = Wf + (size_t)hs * 4096 + l;  // [(g*2+t)*8+ks] stride 64
  const size_t o1 = (size_t)Btot * DH;
  const int wcol = (l & 31) * 4;

  float bb[4][2];
  #pragma unroll
  for (int g = 0; g < 4; ++g)
    #pragma unroll
    for (int t = 0; t < 2; ++t)
      bb[g][t] = bcat[g * 128 + hs * 32 + t * 16 + l15];

  f32x4 acc[2][4][2];
  float cr[2][2][4];

  auto packwr = [&](bf16x8* bp, const f32x4& v0, const f32x4& v1, int slot){
    i32x4 p;
    p[0] = pk2(v0[0], v0[1]); p[1] = pk2(v0[2], v0[3]);
    p[2] = pk2(v1[0], v1[1]); p[3] = pk2(v1[2], v1[3]);
    bp[srow * 32 + (slot ^ swz)] = __builtin_bit_cast(bf16x8, p);
  };
  auto zacc = [&](){
    #pragma unroll
    for (int m = 0; m < 2; ++m)
      #pragma unroll
      for (int g = 0; g < 4; ++g)
        #pragma unroll
        for (int t = 0; t < 2; ++t)
          acc[m][g][t] = (f32x4){0.f, 0.f, 0.f, 0.f};
  };
  auto khalf = [&](const bf16x8* bp, int kb){
    #pragma unroll
    for (int ks = kb; ks < kb + 4; ++ks){
      bf16x8 a[2];
      #pragma unroll
      for (int m = 0; m < 2; ++m){
        const int row = m * 16 + l15;
        a[m] = bp[row * 32 + ((ks * 4 + lg) ^ (row & 7))];
      }
      #pragma unroll
      for (int g = 0; g < 4; ++g){
        #pragma unroll
        for (int t = 0; t < 2; ++t){
          bf16x8 bw = wv[(((g * 2 + t) * 8) + ks) * 64];
          acc[0][g][t] = __builtin_amdgcn_mfma_f32_16x16x32_bf16(a[0], bw, acc[0][g][t], 0, 0, 0);
          acc[1][g][t] = __builtin_amdgcn_mfma_f32_16x16x32_bf16(a[1], bw, acc[1][g][t], 0, 0, 0);
        }
      }
    }
  };
  auto loadc = [&](size_t rb){
    #pragma unroll
    for (int m = 0; m < 2; ++m)
      #pragma unroll
      for (int t = 0; t < 2; ++t)
        #pragma unroll
        for (int r = 0; r < 4; ++r)
          cr[m][t][r] = __builtin_nontemporal_load(
              cin + (rb + m * 16 + lg * 4 + r) * DH + hs * 32 + t * 16 + l15);
  };
  // gates: h -> t_ls (swizzled), c_new -> cr in place
  auto gatewr = [&](float* t_ls){
    #pragma unroll
    for (int m = 0; m < 2; ++m){
      #pragma unroll
      for (int r = 0; r < 4; ++r){
        const int rl = m * 16 + lg * 4 + r;
        const int swp = (rl & 7) << 2;
        #pragma unroll
        for (int t = 0; t < 2; ++t){
          const int c = hs * 32 + t * 16 + l15;
          float gi = acc[m][0][t][r] + bb[0][t];
          float gf = acc[m][1][t][r] + bb[1][t];
          float gc = acc[m][2][t][r] + bb[2][t];
          float go = acc[m][3][t][r] + bb[3][t];
          float i_t = fsigmoid(gi);
          float f_t = fsigmoid(gf);
          float g_t = ftanhf(gc);
          float o_t = fsigmoid(go);
          float cn = f_t * cr[m][t][r] + i_t * g_t;
          float hn = o_t * ftanhf(cn);
          t_ls[rl * DH + (c ^ swp)] = hn;
          cr[m][t][r] = cn;
        }
      }
    }
  };
  auto cwr = [&](float* t_ls){
    #pragma unroll
    for (int m = 0; m < 2; ++m)
      #pragma unroll
      for (int r = 0; r < 4; ++r){
        const int rl = m * 16 + lg * 4 + r;
        const int swp = (rl & 7) << 2;
        #pragma unroll
        for (int t = 0; t < 2; ++t){
          const int c = hs * 32 + t * 16 + l15;
          t_ls[rl * DH + (c ^ swp)] = cr[m][t][r];
        }
      }
  };
  auto storeHH = [&](const float* t_ls, size_t rb){
    #pragma unroll
    for (int j = 0; j < 4; ++j){
      const int row = hs * 8 + j * 2 + (l >> 5);
      const int sw2 = (row & 7) << 2;
      f32x4 v = *(const f32x4*)&t_ls[row * DH + (wcol ^ sw2)];
      float* po = out + (rb + row) * DH + wcol;
      __builtin_nontemporal_store(v, (f32x4*)(po));
      __builtin_nontemporal_store(v, (f32x4*)(po + o1));
    }
  };
  auto storeC = [&](const float* t_ls, size_t rb){
    #pragma unroll
    for (int j = 0; j < 4; ++j){
      const int row = hs * 8 + j * 2 + (l >> 5);
      const int sw2 = (row & 7) << 2;
      f32x4 v = *(const f32x4*)&t_ls[row * DH + (wcol ^ sw2)];
      __builtin_nontemporal_store(v, (f32x4*)(out + 2 * o1 + (rb + row) * DH + wcol));
    }
  };

  // ---------------- prologue: tile0 x/h/c -> regs, pack -> buf0
  {
    const float* px = x   + (rowb0 + srow) * DH + scol;
    const float* ph = hin + (rowb0 + srow) * DH + scol;
    f32x4 a0 = __builtin_nontemporal_load((const f32x4*)(px));
    f32x4 a1 = __builtin_nontemporal_load((const f32x4*)(px + 4));
    f32x4 a2 = __builtin_nontemporal_load((const f32x4*)(px + 8));
    f32x4 a3 = __builtin_nontemporal_load((const f32x4*)(px + 12));
    f32x4 b0 = __builtin_nontemporal_load((const f32x4*)(ph));
    f32x4 b1 = __builtin_nontemporal_load((const f32x4*)(ph + 4));
    f32x4 b2 = __builtin_nontemporal_load((const f32x4*)(ph + 8));
    f32x4 b3 = __builtin_nontemporal_load((const f32x4*)(ph + 12));
    loadc(rowb0);
    packwr(buf0, a0, a1, s0);      packwr(buf0, a2, a3, s0 + 1);
    packwr(buf0, b0, b1, 16 + s0); packwr(buf0, b2, b3, 16 + s0 + 1);
  }
  __syncthreads();                                   // bar A

  // ---------------- k0 (buf0) with tile1 staging folded in
  zacc();
  {
    const float* px = x + (rowb1 + srow) * DH + scol;
    f32x4 a0 = __builtin_nontemporal_load((const f32x4*)(px));
    f32x4 a1 = __builtin_nontemporal_load((const f32x4*)(px + 4));
    f32x4 a2 = __builtin_nontemporal_load((const f32x4*)(px + 8));
    f32x4 a3 = __builtin_nontemporal_load((const f32x4*)(px + 12));
    khalf(buf0, 0);
    packwr(buf1, a0, a1, s0); packwr(buf1, a2, a3, s0 + 1);
  }
  {
    const float* ph = hin + (rowb1 + srow) * DH + scol;
    f32x4 b0 = __builtin_nontemporal_load((const f32x4*)(ph));
    f32x4 b1 = __builtin_nontemporal_load((const f32x4*)(ph + 4));
    f32x4 b2 = __builtin_nontemporal_load((const f32x4*)(ph + 8));
    f32x4 b3 = __builtin_nontemporal_load((const f32x4*)(ph + 12));
    khalf(buf0, 4);
    packwr(buf1, b0, b1, 16 + s0); packwr(buf1, b2, b3, 16 + s0 + 1);
  }
  __syncthreads();                                   // bar B: buf0 free, buf1 ready

  // ---------------- epi0 via buf0 (cr holds c0; gates consume acc0)
  gatewr((float*)buf0);
  __syncthreads();                                   // bar C
  storeHH((float*)buf0, rowb0);
  __syncthreads();                                   // bar D
  cwr((float*)buf0);
  __syncthreads();                                   // bar E
  storeC((float*)buf0, rowb0);

  // cr1 loads: overlap with k1 below
  loadc(rowb1);

  // ---------------- k1 (buf1)
  zacc();
  khalf(buf1, 0);
  khalf(buf1, 4);
  __syncthreads();                                   // bar F: buf1 free

  // ---------------- epi1 via buf1
  gatewr((float*)buf1);
  __syncthreads();
  storeHH((float*)buf1, rowb1);
  __syncthreads();
  cwr((float*)buf1);
  __syncthreads();
  storeC((float*)buf1, rowb1);
}

extern "C" void kernel_launch(void* const* d_in, const int* in_sizes, int n_in,
                              void* d_out, int out_size, void* d_ws, size_t ws_size,
                              hipStream_t stream){
  const float* x  = (const float*)d_in[0];
  const float* ht = (const float*)d_in[1];
  const float* ct = (const float*)d_in[2];
  u16x8* Wf   = (u16x8*)d_ws;                        // 16384 * 16B = 256KB
  float* bcat = (float*)((char*)d_ws + 16384 * 16);  // +2KB
  const int Btot = in_sizes[0] / DH;

  prep_weights<<<64, 256, 0, stream>>>(
      (const float*)d_in[3],  (const float*)d_in[4],  (const float*)d_in[5],
      (const float*)d_in[6],  (const float*)d_in[7],  (const float*)d_in[8],
      (const float*)d_in[9],  (const float*)d_in[10], (const float*)d_in[11],
      (const float*)d_in[12], (const float*)d_in[13], (const float*)d_in[14],
      Wf, bcat);

  lstm_fused<<<Btot / (2 * TR), 256, 0, stream>>>(x, ht, ct, (const bf16x8*)Wf, bcat,
                                                  (float*)d_out, Btot);
}

// Round 14
// 367.860 us; speedup vs baseline: 3.7253x; 1.1834x over previous
//
#include <hip/hip_runtime.h>

#define DH 128   // D_IN == D_H == 128
#define TR 32    // rows per tile (per block)

typedef __attribute__((ext_vector_type(8))) short bf16x8;
typedef __attribute__((ext_vector_type(8))) unsigned short u16x8;
typedef __attribute__((ext_vector_type(4))) float f32x4;
typedef __attribute__((ext_vector_type(4))) int   i32x4;

__device__ inline unsigned rnd_bf16(float f){
  unsigned u = __builtin_bit_cast(unsigned, f);
  u += 0x7fffu + ((u >> 16) & 1u);   // RNE
  return u;
}
__device__ inline int pk2(float a, float b){
  unsigned ua = rnd_bf16(a), ub = rnd_bf16(b);
  return (int)((ua >> 16) | (ub & 0xffff0000u));
}
__device__ inline float fsigmoid(float v){
  float e = __builtin_amdgcn_exp2f(v * -1.442695040888963f);
  return __builtin_amdgcn_rcpf(1.0f + e);
}
__device__ inline float ftanhf(float v){
  float e = __builtin_amdgcn_exp2f(v * 2.885390081777927f); // e^{2v}
  return 1.0f - 2.0f * __builtin_amdgcn_rcpf(1.0f + e);
}
__device__ inline void gload_lds16(const float* g, float* l){
  __builtin_amdgcn_global_load_lds(
      (const __attribute__((address_space(1))) void*)g,
      (__attribute__((address_space(3))) void*)l, 16, 0, 0);
}

// Wf[hs 4][g 4][t 2][ks 8][lane 64] 16B fragments: lane (l15,lg) holds
// ncol = g*128 + hs*32 + t*16 + l15, k = ks*32 + lg*8 .. +8 (k<128: W_x, else W_h).
__global__ void prep_weights(const float* __restrict__ Wxi, const float* __restrict__ Whi, const float* __restrict__ bi,
                             const float* __restrict__ Wxf, const float* __restrict__ Whf, const float* __restrict__ bf_,
                             const float* __restrict__ Wxc, const float* __restrict__ Whc, const float* __restrict__ bc,
                             const float* __restrict__ Wxo, const float* __restrict__ Who, const float* __restrict__ bo,
                             u16x8* __restrict__ Wf, float* __restrict__ bcat){
  int gid  = blockIdx.x * 256 + threadIdx.x;   // 0..16383
  int lane = gid & 63;
  int ks   = (gid >> 6) & 7;
  int t    = (gid >> 9) & 1;
  int g    = (gid >> 10) & 3;
  int hsv  = (gid >> 12) & 3;
  int l15 = lane & 15, lg = lane >> 4;
  int hcol = hsv * 32 + t * 16 + l15;
  int kb   = ks * 32 + lg * 8;
  const float* Wx = (g == 0) ? Wxi : (g == 1) ? Wxf : (g == 2) ? Wxc : Wxo;
  const float* Wh = (g == 0) ? Whi : (g == 1) ? Whf : (g == 2) ? Whc : Who;
  u16x8 o;
  #pragma unroll
  for (int j = 0; j < 8; ++j){
    int k = kb + j;
    float v = (k < 128) ? Wx[k * DH + hcol] : Wh[(k - 128) * DH + hcol];
    o[j] = (unsigned short)(rnd_bf16(v) >> 16);
  }
  Wf[gid] = o;
  if (gid < 512){
    int gg = gid >> 7, hc = gid & 127;
    const float* bp = (gg == 0) ? bi : (gg == 1) ? bf_ : (gg == 2) ? bc : bo;
    bcat[gid] = bp[hc];
  }
}

// One 32-row tile per block. 256 thr = 4 waves; wave w owns h-cols
// [w*32,+32) for all 4 gates (lane-local elementwise).
// x/h staged f32 via global_load_lds (async DMA, zero VGPR held), source
// chunk-swizzled ch^((row&7)<<1) so k-loop f32 reads are ~2-way-conflict.
// bf16 pack happens in the k-loop (overlaps MFMA). NT c-loads + NT
// 1KiB-contiguous stores (R9 policy). Epilogue h->xs, c->hsb in one pass.
__global__ __launch_bounds__(256, 4)
void lstm_fused(const float* __restrict__ x, const float* __restrict__ hin,
                const float* __restrict__ cin, const bf16x8* __restrict__ Wf,
                const float* __restrict__ bcat, float* __restrict__ out, int Btot){
  __shared__ __attribute__((aligned(16))) float xs [TR * DH];  // 16 KB
  __shared__ __attribute__((aligned(16))) float hsb[TR * DH];  // 16 KB

  const int tid = threadIdx.x;
  const int l   = tid & 63;
  const int hs  = tid >> 6;        // wave id = col-slice 0..3
  const int l15 = l & 15;
  const int lg  = l >> 4;          // 0..3
  const size_t rowb = (size_t)blockIdx.x * TR;

  // ---- async stage x,h -> LDS. Per wave: rows [hs*8, hs*8+8), 4 instrs per
  // matrix, each 1 KiB (2 rows). lane l -> row base+ (l>>5), lds chunk l&31;
  // global chunk = (l&31) ^ ((row&7)<<1)  (16B chunk units).
  {
    const int lrow = l >> 5;            // 0/1
    const int lch  = l & 31;
    #pragma unroll
    for (int j = 0; j < 4; ++j){
      const int brow = hs * 8 + j * 2;
      const int row  = brow + lrow;
      const int gch  = lch ^ ((row & 7) << 1);
      const float* gx = x   + (rowb + row) * DH + gch * 4;
      const float* gh = hin + (rowb + row) * DH + gch * 4;
      gload_lds16(gx, &xs [brow * DH]);
      gload_lds16(gh, &hsb[brow * DH]);
    }
  }

  // ---- c prefetch (nontemporal), in flight across the barrier
  float cr[2][2][4];
  #pragma unroll
  for (int m = 0; m < 2; ++m)
    #pragma unroll
    for (int t = 0; t < 2; ++t)
      #pragma unroll
      for (int r = 0; r < 4; ++r)
        cr[m][t][r] = __builtin_nontemporal_load(
            cin + (rowb + m * 16 + lg * 4 + r) * DH + hs * 32 + t * 16 + l15);

  float bb[4][2];
  #pragma unroll
  for (int g = 0; g < 4; ++g)
    #pragma unroll
    for (int t = 0; t < 2; ++t)
      bb[g][t] = bcat[g * 128 + hs * 32 + t * 16 + l15];

  __syncthreads();   // drains vmcnt -> LDS tiles ready

  const bf16x8* wv = Wf + (size_t)hs * 4096 + l;  // [(g*2+t)*8+ks] stride 64

  f32x4 acc[2][4][2];
  #pragma unroll
  for (int m = 0; m < 2; ++m)
    #pragma unroll
    for (int g = 0; g < 4; ++g)
      #pragma unroll
      for (int t = 0; t < 2; ++t)
        acc[m][g][t] = (f32x4){0.f, 0.f, 0.f, 0.f};

  #pragma unroll
  for (int ks = 0; ks < 8; ++ks){
    const float* sb = (ks < 4) ? xs : hsb;
    const int ksl = ks & 3;
    bf16x8 a[2];
    #pragma unroll
    for (int m = 0; m < 2; ++m){
      const int row = m * 16 + l15;
      const int sw  = (row & 7) << 1;
      const int c0  = ksl * 8 + lg * 2;          // 16B-chunk index
      f32x4 f0 = *(const f32x4*)&sb[row * DH + ((c0     ^ sw) << 2)];
      f32x4 f1 = *(const f32x4*)&sb[row * DH + (((c0+1) ^ sw) << 2)];
      i32x4 p;
      p[0] = pk2(f0[0], f0[1]); p[1] = pk2(f0[2], f0[3]);
      p[2] = pk2(f1[0], f1[1]); p[3] = pk2(f1[2], f1[3]);
      a[m] = __builtin_bit_cast(bf16x8, p);
    }
    #pragma unroll
    for (int g = 0; g < 4; ++g){
      #pragma unroll
      for (int t = 0; t < 2; ++t){
        bf16x8 bw = wv[(((g * 2 + t) * 8) + ks) * 64];
        acc[0][g][t] = __builtin_amdgcn_mfma_f32_16x16x32_bf16(a[0], bw, acc[0][g][t], 0, 0, 0);
        acc[1][g][t] = __builtin_amdgcn_mfma_f32_16x16x32_bf16(a[1], bw, acc[1][g][t], 0, 0, 0);
      }
    }
  }
  __syncthreads();   // all LDS reads done; xs/hsb reusable

  // ---- gate math; h -> xs, c -> hsb (f32, swizzle col^((row&7)<<2)), one pass
  #pragma unroll
  for (int m = 0; m < 2; ++m){
    #pragma unroll
    for (int r = 0; r < 4; ++r){
      const int rl = m * 16 + lg * 4 + r;       // local row 0..31
      const int swp = (rl & 7) << 2;
      #pragma unroll
      for (int t = 0; t < 2; ++t){
        const int c = hs * 32 + t * 16 + l15;   // col 0..127
        float gi = acc[m][0][t][r] + bb[0][t];
        float gf = acc[m][1][t][r] + bb[1][t];
        float gc = acc[m][2][t][r] + bb[2][t];
        float go = acc[m][3][t][r] + bb[3][t];
        float i_t = fsigmoid(gi);
        float f_t = fsigmoid(gf);
        float g_t = ftanhf(gc);
        float o_t = fsigmoid(go);
        float cn = f_t * cr[m][t][r] + i_t * g_t;
        float hn = o_t * ftanhf(cn);
        xs [rl * DH + (c ^ swp)] = hn;
        hsb[rl * DH + (c ^ swp)] = cn;
      }
    }
  }
  __syncthreads();

  // ---- stores: wave hs owns rows [hs*8,+8); lane l -> row j*2+(l>>5),
  // colf (l&31)*4 => each instruction = 1KiB contiguous NT burst.
  const size_t o1 = (size_t)Btot * DH;
  const int wcol = (l & 31) * 4;
  #pragma unroll
  for (int j = 0; j < 4; ++j){
    const int row = hs * 8 + j * 2 + (l >> 5);
    const int sw2 = (row & 7) << 2;
    f32x4 vh = *(const f32x4*)&xs [row * DH + (wcol ^ sw2)];
    f32x4 vc = *(const f32x4*)&hsb[row * DH + (wcol ^ sw2)];
    float* po = out + (rowb + row) * DH + wcol;
    __builtin_nontemporal_store(vh, (f32x4*)(po));
    __builtin_nontemporal_store(vh, (f32x4*)(po + o1));
    __builtin_nontemporal_store(vc, (f32x4*)(po + 2 * o1));
  }
}

extern "C" void kernel_launch(void* const* d_in, const int* in_sizes, int n_in,
                              void* d_out, int out_size, void* d_ws, size_t ws_size,
                              hipStream_t stream){
  const float* x  = (const float*)d_in[0];
  const float* ht = (const float*)d_in[1];
  const float* ct = (const float*)d_in[2];
  u16x8* Wf   = (u16x8*)d_ws;                        // 16384 * 16B = 256KB
  float* bcat = (float*)((char*)d_ws + 16384 * 16);  // +2KB
  const int Btot = in_sizes[0] / DH;

  prep_weights<<<64, 256, 0, stream>>>(
      (const float*)d_in[3],  (const float*)d_in[4],  (const float*)d_in[5],
      (const float*)d_in[6],  (const float*)d_in[7],  (const float*)d_in[8],
      (const float*)d_in[9],  (const float*)d_in[10], (const float*)d_in[11],
      (const float*)d_in[12], (const float*)d_in[13], (const float*)d_in[14],
      Wf, bcat);

  lstm_fused<<<Btot / TR, 256, 0, stream>>>(x, ht, ct, (const bf16x8*)Wf, bcat,
                                            (float*)d_out, Btot);
}

// Round 15
// 255.369 us; speedup vs baseline: 5.3663x; 1.4405x over previous
//
#include <hip/hip_runtime.h>

#define DH 128   // D_IN == D_H == 128
#define TR 32    // rows per tile (per block)

typedef __attribute__((ext_vector_type(8))) short bf16x8;
typedef __attribute__((ext_vector_type(8))) unsigned short u16x8;
typedef __attribute__((ext_vector_type(4))) float f32x4;
typedef __attribute__((ext_vector_type(4))) int   i32x4;

__device__ inline unsigned rnd_bf16(float f){
  unsigned u = __builtin_bit_cast(unsigned, f);
  u += 0x7fffu + ((u >> 16) & 1u);   // RNE
  return u;
}
__device__ inline int pk2(float a, float b){
  unsigned ua = rnd_bf16(a), ub = rnd_bf16(b);
  return (int)((ua >> 16) | (ub & 0xffff0000u));
}
__device__ inline float fsigmoid(float v){
  float e = __builtin_amdgcn_exp2f(v * -1.442695040888963f);
  return __builtin_amdgcn_rcpf(1.0f + e);
}
__device__ inline float ftanhf(float v){
  float e = __builtin_amdgcn_exp2f(v * 2.885390081777927f); // e^{2v}
  return 1.0f - 2.0f * __builtin_amdgcn_rcpf(1.0f + e);
}

// Wf[hs 4][g 4][t 2][ks 8][lane 64] 16B fragments: lane (l15,lg) holds
// ncol = g*128 + hs*32 + t*16 + l15, k = ks*32 + lg*8 .. +8 (k<128: W_x, else W_h).
__global__ void prep_weights(const float* __restrict__ Wxi, const float* __restrict__ Whi, const float* __restrict__ bi,
                             const float* __restrict__ Wxf, const float* __restrict__ Whf, const float* __restrict__ bf_,
                             const float* __restrict__ Wxc, const float* __restrict__ Whc, const float* __restrict__ bc,
                             const float* __restrict__ Wxo, const float* __restrict__ Who, const float* __restrict__ bo,
                             u16x8* __restrict__ Wf, float* __restrict__ bcat){
  int gid  = blockIdx.x * 256 + threadIdx.x;   // 0..16383
  int lane = gid & 63;
  int ks   = (gid >> 6) & 7;
  int t    = (gid >> 9) & 1;
  int g    = (gid >> 10) & 3;
  int hsv  = (gid >> 12) & 3;
  int l15 = lane & 15, lg = lane >> 4;
  int hcol = hsv * 32 + t * 16 + l15;
  int kb   = ks * 32 + lg * 8;
  const float* Wx = (g == 0) ? Wxi : (g == 1) ? Wxf : (g == 2) ? Wxc : Wxo;
  const float* Wh = (g == 0) ? Whi : (g == 1) ? Whf : (g == 2) ? Whc : Who;
  u16x8 o;
  #pragma unroll
  for (int j = 0; j < 8; ++j){
    int k = kb + j;
    float v = (k < 128) ? Wx[k * DH + hcol] : Wh[(k - 128) * DH + hcol];
    o[j] = (unsigned short)(rnd_bf16(v) >> 16);
  }
  Wf[gid] = o;
  if (gid < 512){
    int gg = gid >> 7, hc = gid & 127;
    const float* bp = (gg == 0) ? bi : (gg == 1) ? bf_ : (gg == 2) ? bc : bo;
    bcat[gid] = bp[hc];
  }
}

// One 32-row tile per block. 512 thr = 8 waves; wave w owns h-cols
// [w*16,+16) for all 4 gates (lane-local elementwise; acc = 32 regs/thread).
// Small per-wave state => __launch_bounds__(512,6) caps regs at 85 ->
// 3 blocks/CU = 24 waves/CU (vs 16 for the 32-col decomposition).
// NT loads/stores; bf16 LDS staging; LDS-transpose epilogue, 1KiB NT bursts.
__global__ __launch_bounds__(512, 6)
void lstm_fused(const float* __restrict__ x, const float* __restrict__ hin,
                const float* __restrict__ cin, const bf16x8* __restrict__ Wf,
                const float* __restrict__ bcat, float* __restrict__ out, int Btot){
  __shared__ __attribute__((aligned(16))) unsigned char smem[32768];
  bf16x8* xh  = (bf16x8*)smem;              // staging tile, 32 rows x 32 slots (16 KB)
  float*  hls = (float*)smem;               // epilogue h plane (reuse, 16 KB)
  float*  cls = (float*)(smem + 16384);     // epilogue c plane (16 KB)

  const int tid = threadIdx.x;
  const int l   = tid & 63;
  const int wid = tid >> 6;        // wave id 0..7 = 16-col slice
  const int l15 = l & 15;
  const int lg  = l >> 4;          // 0..3
  const int col = wid * 16 + l15;  // h-col this lane owns
  const size_t rowb = (size_t)blockIdx.x * TR;

  // ---- staging loads (nontemporal): thread covers (row tid>>4, 8 floats)
  const int srow = tid >> 4;       // 0..31
  const int sc   = tid & 15;       // 8-float slot within row
  const float* px = x   + (rowb + srow) * DH + sc * 8;
  const float* ph = hin + (rowb + srow) * DH + sc * 8;
  f32x4 x0 = __builtin_nontemporal_load((const f32x4*)(px));
  f32x4 x1 = __builtin_nontemporal_load((const f32x4*)(px + 4));
  f32x4 h0 = __builtin_nontemporal_load((const f32x4*)(ph));
  f32x4 h1 = __builtin_nontemporal_load((const f32x4*)(ph + 4));

  // ---- c prefetch (nontemporal): 8 scalars (m,r)
  float cr[2][4];
  #pragma unroll
  for (int m = 0; m < 2; ++m)
    #pragma unroll
    for (int r = 0; r < 4; ++r)
      cr[m][r] = __builtin_nontemporal_load(
          cin + (rowb + m * 16 + lg * 4 + r) * DH + col);

  // ---- pack + LDS write (slot swizzle s^(row&7) within each 16-slot half)
  {
    const int sw = srow & 7;
    i32x4 p;
    p[0] = pk2(x0[0], x0[1]); p[1] = pk2(x0[2], x0[3]);
    p[2] = pk2(x1[0], x1[1]); p[3] = pk2(x1[2], x1[3]);
    xh[srow * 32 + ( sc       ^ sw)] = __builtin_bit_cast(bf16x8, p);
    p[0] = pk2(h0[0], h0[1]); p[1] = pk2(h0[2], h0[3]);
    p[2] = pk2(h1[0], h1[1]); p[3] = pk2(h1[2], h1[3]);
    xh[srow * 32 + ((16 + sc) ^ sw)] = __builtin_bit_cast(bf16x8, p);
  }
  __syncthreads();

  float bb[4];
  #pragma unroll
  for (int g = 0; g < 4; ++g)
    bb[g] = bcat[g * 128 + col];

  // wave's weight stream: slice (hs = wid>>1, t = wid&1) of Wf
  const bf16x8* wv = Wf + (size_t)(wid >> 1) * 4096 + l;
  const int tw = wid & 1;

  f32x4 acc[2][4];
  #pragma unroll
  for (int m = 0; m < 2; ++m)
    #pragma unroll
    for (int g = 0; g < 4; ++g)
      acc[m][g] = (f32x4){0.f, 0.f, 0.f, 0.f};

  #pragma unroll
  for (int ks = 0; ks < 8; ++ks){
    bf16x8 a[2];
    #pragma unroll
    for (int m = 0; m < 2; ++m){
      const int row = m * 16 + l15;
      a[m] = xh[row * 32 + ((ks * 4 + lg) ^ (row & 7))];
    }
    #pragma unroll
    for (int g = 0; g < 4; ++g){
      bf16x8 bw = wv[(((g * 2 + tw) * 8) + ks) * 64];
      acc[0][g] = __builtin_amdgcn_mfma_f32_16x16x32_bf16(a[0], bw, acc[0][g], 0, 0, 0);
      acc[1][g] = __builtin_amdgcn_mfma_f32_16x16x32_bf16(a[1], bw, acc[1][g], 0, 0, 0);
    }
  }
  __syncthreads();   // k-loop LDS reads done everywhere; safe to reuse smem

  // ---- gate math; h -> hls, c -> cls (swizzle col^((row&7)<<2))
  #pragma unroll
  for (int m = 0; m < 2; ++m){
    #pragma unroll
    for (int r = 0; r < 4; ++r){
      const int rl = m * 16 + lg * 4 + r;       // local row 0..31
      const int swp = (rl & 7) << 2;
      float gi = acc[m][0][r] + bb[0];
      float gf = acc[m][1][r] + bb[1];
      float gc = acc[m][2][r] + bb[2];
      float go = acc[m][3][r] + bb[3];
      float i_t = fsigmoid(gi);
      float f_t = fsigmoid(gf);
      float g_t = ftanhf(gc);
      float o_t = fsigmoid(go);
      float cn = f_t * cr[m][r] + i_t * g_t;
      float hn = o_t * ftanhf(cn);
      hls[rl * DH + (col ^ swp)] = hn;
      cls[rl * DH + (col ^ swp)] = cn;
    }
  }
  __syncthreads();

  // ---- stores: wave wid owns rows [wid*4, wid*4+4); each instruction:
  // lane l -> row j*2+(l>>5), colf (l&31)*4 => 1KiB contiguous NT burst.
  const size_t o1 = (size_t)Btot * DH;
  const int wcol = (l & 31) * 4;
  #pragma unroll
  for (int j = 0; j < 2; ++j){
    const int row = wid * 4 + j * 2 + (l >> 5);
    const int sw2 = (row & 7) << 2;
    f32x4 vh = *(const f32x4*)&hls[row * DH + (wcol ^ sw2)];
    f32x4 vc = *(const f32x4*)&cls[row * DH + (wcol ^ sw2)];
    float* po = out + (rowb + row) * DH + wcol;
    __builtin_nontemporal_store(vh, (f32x4*)(po));
    __builtin_nontemporal_store(vh, (f32x4*)(po + o1));
    __builtin_nontemporal_store(vc, (f32x4*)(po + 2 * o1));
  }
}

extern "C" void kernel_launch(void* const* d_in, const int* in_sizes, int n_in,
                              void* d_out, int out_size, void* d_ws, size_t ws_size,
                              hipStream_t stream){
  const float* x  = (const float*)d_in[0];
  const float* ht = (const float*)d_in[1];
  const float* ct = (const float*)d_in[2];
  u16x8* Wf   = (u16x8*)d_ws;                        // 16384 * 16B = 256KB
  float* bcat = (float*)((char*)d_ws + 16384 * 16);  // +2KB
  const int Btot = in_sizes[0] / DH;

  prep_weights<<<64, 256, 0, stream>>>(
      (const float*)d_in[3],  (const float*)d_in[4],  (const float*)d_in[5],
      (const float*)d_in[6],  (const float*)d_in[7],  (const float*)d_in[8],
      (const float*)d_in[9],  (const float*)d_in[10], (const float*)d_in[11],
      (const float*)d_in[12], (const float*)d_in[13], (const float*)d_in[14],
      Wf, bcat);

  lstm_fused<<<Btot / TR, 512, 0, stream>>>(x, ht, ct, (const bf16x8*)Wf, bcat,
                                            (float*)d_out, Btot);
}